// Round 9
// baseline (187.918 us; speedup 1.0000x reference)
//
#include <hip/hip_runtime.h>
#include <math.h>

#define HDIM 128
#define EPSV 1e-5f
#define TOLV 1e-7f
#define MINSCORE 0.1f
#define PMAX 2048
#define KSEG 16
#define ESEG 64
#define NT 1024
#define NSL 16          // producer slices per graph

// ===========================================================================
// K1: one block per graph. LDS in-degree histogram -> degI, hA = x@Wa,
// zero agg, zero done[g].
// ===========================================================================
__global__ __launch_bounds__(NT) void d1(
        const float* __restrict__ x, const int* __restrict__ dst,
        const float* __restrict__ Wa, float* __restrict__ hA,
        unsigned* __restrict__ degI, float* __restrict__ agg,
        int* __restrict__ done, int P, int epg) {
    __shared__ unsigned degH[PMAX];
    const int g = blockIdx.x, t = threadIdx.x;
    const int base = g * P, e0 = g * epg, e1 = e0 + epg;
    for (int j = t; j < P; j += NT) degH[j] = 0u;
    __syncthreads();
    for (int e = e0 + t; e < e1; e += NT) {
        unsigned d = (unsigned)(dst[e] - base);
        if (d < (unsigned)P) atomicAdd(&degH[d], 1u);
    }
    __syncthreads();
    const float wa0 = Wa[0], wa1 = Wa[1];
    const float2* __restrict__ x2 = (const float2*)x;
    for (int j = t; j < P; j += NT) {
        int i = base + j;
        float2 xv = x2[i];
        hA[i]   = xv.x * wa0 + xv.y * wa1;
        degI[i] = degH[j];
        agg[i]  = 0.0f;
    }
    if (t == 0) done[g] = 0;
}

__device__ __forceinline__ float agentLoadF(const float* p) {
    return __hip_atomic_load(p, __ATOMIC_RELAXED, __HIP_MEMORY_SCOPE_AGENT);
}

// ===========================================================================
// K2 (fused): blocks [0, nProd) = producers (scatter one edge slice, fence,
// bump done[g]); blocks [nProd, nProd+G) = consumers (one per graph: spin on
// done[g]==NSL, then softmax -> keep -> layers -> pool -> head).
// Consumers read agg with agent-scope atomic loads (per-XCD L2 not coherent
// for same-kernel cross-block data; plain loads could see stale lines).
// ===========================================================================
__global__ __launch_bounds__(NT) void d23(
        const float* __restrict__ x, const int* __restrict__ src,
        const int* __restrict__ dst, const float* __restrict__ hA,
        const unsigned* __restrict__ degI, float* __restrict__ agg,
        int* __restrict__ done,
        const float* __restrict__ bA, const float* __restrict__ wt,
        const float* __restrict__ W0, const float* __restrict__ b0,
        const float* __restrict__ g0, const float* __restrict__ be0,
        const float* __restrict__ m0, const float* __restrict__ v0,
        const float* __restrict__ W1, const float* __restrict__ b1,
        const float* __restrict__ g1, const float* __restrict__ be1,
        const float* __restrict__ m1, const float* __restrict__ v1,
        const float* __restrict__ W2, const float* __restrict__ b2,
        const float* __restrict__ g2, const float* __restrict__ be2,
        const float* __restrict__ m2, const float* __restrict__ v2,
        const float* __restrict__ Wf, const float* __restrict__ bfv,
        float* __restrict__ out, int P, int epg, int eps, int qpx, int nProd) {
    const int bid = blockIdx.x;

    // ---------------- producers ----------------
    if (bid < nProd) {
        int g, sl;
        if (qpx > 0) {            // same-graph blocks -> same XCD (G%8==0)
            int c = bid & 7, j = bid >> 3;
            g = c + 8 * (j % qpx);
            sl = j / qpx;
        } else { g = bid / NSL; sl = bid - g * NSL; }
        const int e0 = g * epg + sl * eps;
        int e1 = e0 + eps; int eg = g * epg + epg; if (e1 > eg) e1 = eg;
        for (int e = e0 + threadIdx.x; e < e1; e += NT) {
            int s = src[e], d = dst[e];
            float nrm = rsqrtf(1.0f + (float)degI[s]) * rsqrtf(1.0f + (float)degI[d]);
            atomicAdd(&agg[d], hA[s] * nrm);
        }
        __syncthreads();          // drain this block's atomics (vmcnt)
        __threadfence();          // order them before the done increment
        if (threadIdx.x == 0) atomicAdd(&done[g], 1);
        return;
    }

    // ---------------- consumer: one block per graph ----------------
    const int g = bid - nProd, t = threadIdx.x;
    const int lane = t & 63, wid = t >> 6;       // 16 waves
    const int base = g * P;
    const int e0 = g * epg, e1 = e0 + epg;

    __shared__ float scL[PMAX];
    __shared__ float hbufL[KSEG * HDIM], tbufL[KSEG * HDIM], redM[8 * HDIM];
    __shared__ float redA[16], redB[16], mzS[2];
    __shared__ int   keptL[KSEG];
    __shared__ float degkL[KSEG], pooledL[HDIM];
    __shared__ int   aSL[ESEG], aDL[ESEG];
    __shared__ int   kcnt, ecnt;

    if (t == 0) { kcnt = 0; ecnt = 0; }
    if (t < KSEG) degkL[t] = 1.0f;               // self-loop
    const float ba = bA[0], wtk = wt[0];
    const float2* __restrict__ x2 = (const float2*)x;

    // pre-term from K1 data (safe plain loads), overlapped with producer wait
    for (int j = t; j < P; j += NT) {
        int i = base + j;
        float dg = 1.0f + (float)degI[i];
        scL[j] = hA[i] * (1.0f / dg) + ba;       // pre; agg added after spin
    }

    // spin until all NSL producer slices of this graph have landed
    if (t == 0) {
        while (__hip_atomic_load(&done[g], __ATOMIC_ACQUIRE,
                                 __HIP_MEMORY_SCOPE_AGENT) < NSL) { }
    }
    __syncthreads();

    // ---- score (agg via agent-scope loads) + max reduce ----
    float m = -INFINITY;
    for (int j = t; j < P; j += NT) {
        float sc = (agentLoadF(&agg[base + j]) + scL[j]) * wtk;
        scL[j] = sc;
        m = fmaxf(m, sc);
    }
    #pragma unroll
    for (int off = 32; off; off >>= 1) m = fmaxf(m, __shfl_xor(m, off));
    if (lane == 0) redA[wid] = m;
    __syncthreads();
    if (wid == 0) {
        float v = (lane < 16) ? redA[lane] : -INFINITY;
        #pragma unroll
        for (int off = 8; off; off >>= 1) v = fmaxf(v, __shfl_xor(v, off));
        if (lane == 0) mzS[0] = v;
    }
    __syncthreads();
    m = mzS[0];

    // ---- z = sum exp(s - m) ----
    float z = 0.0f;
    for (int j = t; j < P; j += NT) z += expf(scL[j] - m);
    #pragma unroll
    for (int off = 32; off; off >>= 1) z += __shfl_xor(z, off);
    if (lane == 0) redB[wid] = z;
    __syncthreads();
    if (wid == 0) {
        float v = (lane < 16) ? redB[lane] : 0.0f;
        #pragma unroll
        for (int off = 8; off; off >>= 1) v += __shfl_xor(v, off);
        if (lane == 0) mzS[1] = v;
    }
    __syncthreads();
    const float zz = mzS[1];
    // argmax node has exp(0)=1 exactly -> smax = 1/zz (matches reference)
    const float thr = fminf(1.0f / zz - TOLV, MINSCORE);

    // ---- keep + compact; layer-0 rows h0 = x * score ----
    for (int j = t; j < P; j += NT) {
        float sc = expf(scL[j] - m) / zz;
        if (sc > thr) {
            int k = atomicAdd(&kcnt, 1);
            if (k < KSEG) {
                keptL[k] = j;
                float2 xv = x2[base + j];
                hbufL[k * HDIM + 0] = xv.x * sc;
                hbufL[k * HDIM + 1] = xv.y * sc;
            }
        }
    }
    __syncthreads();
    const int kc = kcnt < KSEG ? kcnt : KSEG;

    // ---- membership scan ONLY if more than one node kept ----
    int ec = 0;
    if (kc > 1) {
        for (int e = e0 + t; e < e1; e += NT) {
            int s = src[e] - base, d = dst[e] - base;
            int ks = -1, kd = -1;
            for (int q = 0; q < kc; ++q) {
                int kq = keptL[q];
                if (s == kq) ks = q;
                if (d == kq) kd = q;
            }
            if (ks >= 0 && kd >= 0) {
                int ee = atomicAdd(&ecnt, 1);
                if (ee < ESEG) { aSL[ee] = ks; aDL[ee] = kd; }
                atomicAdd(&degkL[kd], 1.0f);
            }
        }
        __syncthreads();
        ec = ecnt < ESEG ? ecnt : ESEG;
    }

    // ---- 3 GCN layers on kc rows ----
    const int c   = t & (HDIM - 1);
    const int sub = t >> 7;                     // 0..7 split-K groups
    const float* Ws[3]  = {W0, W1, W2};
    const float* bs[3]  = {b0, b1, b2};
    const float* gs[3]  = {g0, g1, g2};
    const float* bes[3] = {be0, be1, be2};
    const float* ms[3]  = {m0, m1, m2};
    const float* vs[3]  = {v0, v1, v2};

    for (int l = 0; l < 3; ++l) {
        const float* W = Ws[l];
        if (l == 0) {
            for (int r = sub; r < kc; r += 8)
                tbufL[r*HDIM+c] = hbufL[r*HDIM+0]*W[c] + hbufL[r*HDIM+1]*W[HDIM+c];
            __syncthreads();
        } else {
            for (int r = 0; r < kc; ++r) {
                float acc = 0.0f;
                const int k0i = sub * 16;
                #pragma unroll
                for (int i = 0; i < 16; ++i)
                    acc += hbufL[r*HDIM+k0i+i] * W[(k0i+i)*HDIM+c];
                redM[sub*HDIM+c] = acc;
                __syncthreads();
                if (t < HDIM) {
                    float s2 = 0.0f;
                    #pragma unroll
                    for (int q = 0; q < 8; ++q) s2 += redM[q*HDIM+c];
                    tbufL[r*HDIM+c] = s2;
                }
                __syncthreads();
            }
        }
        const float bb = bs[l][c];
        const float bscale = gs[l][c] * rsqrtf(vs[l][c] + EPSV);
        const float bmu = ms[l][c], bbe = bes[l][c];
        if (kc == 1) {
            // all active edges are self-edges; agg + self term == t exactly
            if (t < HDIM) {
                float v = tbufL[c] + bb;
                v = fmaxf(v, 0.0f);
                hbufL[c] = (v - bmu) * bscale + bbe;
            }
            __syncthreads();
        } else {
            for (int r = sub; r < kc; r += 8) {
                float a = 0.0f;
                for (int e = 0; e < ec; ++e) {
                    if (aDL[e] == r) {
                        int rs = aSL[e];
                        a += tbufL[rs*HDIM+c] * rsqrtf(degkL[rs]) * rsqrtf(degkL[r]);
                    }
                }
                float v = a + tbufL[r*HDIM+c] * (1.0f/degkL[r]) + bb;
                v = fmaxf(v, 0.0f);
                hbufL[r*HDIM+c] = (v - bmu) * bscale + bbe;
            }
            __syncthreads();
        }
    }

    // ---- max-pool over kept rows ----
    if (t < HDIM) {
        float mm = -INFINITY;
        for (int r = 0; r < kc; ++r) mm = fmaxf(mm, hbufL[r*HDIM+t]);
        pooledL[t] = mm;
    }
    __syncthreads();

    // ---- head: wave r (r<3) computes logits[r] ----
    if (wid < 3) {
        float acc = pooledL[lane]      * Wf[lane*3+wid] +
                    pooledL[lane + 64] * Wf[(lane+64)*3+wid];
        #pragma unroll
        for (int off = 32; off; off >>= 1) acc += __shfl_xor(acc, off);
        if (lane == 0) redA[wid] = acc + bfv[wid];
    }
    __syncthreads();
    if (t == 0) {
        float l0 = redA[0], l1 = redA[1], l2 = redA[2];
        float mm = fmaxf(l0, fmaxf(l1, l2));
        float zs = expf(l0-mm) + expf(l1-mm) + expf(l2-mm);
        float lz = logf(zs) + mm;
        out[g*3+0] = l0 - lz;
        out[g*3+1] = l1 - lz;
        out[g*3+2] = l2 - lz;
    }
}

// ===========================================================================

extern "C" void kernel_launch(void* const* d_in, const int* in_sizes, int n_in,
                              void* d_out, int out_size, void* d_ws, size_t ws_size,
                              hipStream_t stream) {
    const float* x      = (const float*)d_in[0];
    const int*   src    = (const int*)d_in[1];
    const int*   dst    = (const int*)d_in[2];
    const float* W_attn = (const float*)d_in[5];
    const float* b_attn = (const float*)d_in[6];
    const float* w_topk = (const float*)d_in[7];
    float* out = (float*)d_out;

    int N  = in_sizes[3];
    int E  = in_sizes[1];
    int Gn = out_size / 3;
    int Pn = N / Gn;
    int epg = E / Gn;

    // workspace
    char* w = (char*)d_ws;
    auto alloc = [&](size_t bytes) -> void* {
        void* q = (void*)w;
        w += (bytes + 255) & ~size_t(255);
        return q;
    };
    unsigned* degI = (unsigned*)alloc((size_t)N * 4);
    float*    agg  = (float*)alloc((size_t)N * 4);
    float*    hA   = (float*)alloc((size_t)N * 4);
    int*      done = (int*)alloc((size_t)Gn * 4);

    int eps   = (epg + NSL - 1) / NSL;          // edges per producer slice
    int nProd = Gn * NSL;
    int qpx   = (Gn % 8 == 0) ? Gn / 8 : 0;     // producer XCD swizzle on/off

    d1<<<Gn, NT, 0, stream>>>(x, dst, W_attn, hA, degI, agg, done, Pn, epg);
    d23<<<nProd + Gn, NT, 0, stream>>>(x, src, dst, hA, degI, agg, done,
        b_attn, w_topk,
        (const float*)d_in[8],  (const float*)d_in[9],  (const float*)d_in[10],
        (const float*)d_in[11], (const float*)d_in[12], (const float*)d_in[13],
        (const float*)d_in[14], (const float*)d_in[15], (const float*)d_in[16],
        (const float*)d_in[17], (const float*)d_in[18], (const float*)d_in[19],
        (const float*)d_in[20], (const float*)d_in[21], (const float*)d_in[22],
        (const float*)d_in[23], (const float*)d_in[24], (const float*)d_in[25],
        (const float*)d_in[26], (const float*)d_in[27], out, Pn, epg,
        eps, qpx, nProd);
}

// Round 10
// 24.095 us; speedup vs baseline: 7.7991x; 7.7991x over previous
//
#include <hip/hip_runtime.h>
#include <math.h>

#define HDIM 128
#define EPSV 1e-5f
#define TOLV 1e-7f
#define MINSCORE 0.1f
#define PMAX 2048
#define KSEG 16
#define ESEG 64
#define NT 1024
#define NSLA 4          // partial-agg slices per graph (no atomics, no zeroing)

// ===========================================================================
// K_A: 4 blocks per graph. Each block: full per-graph LDS degree histogram
// (16K dst reads, replicated), then scatters its 4K-edge slice into LDS and
// writes a PRIVATE partial array aggP[sl] (plain stores — no global atomics,
// no pre-zeroed memory). Slice 0 also publishes degI. hA recomputed from x.
// ===========================================================================
__global__ __launch_bounds__(NT) void kA(
        const float* __restrict__ x, const int* __restrict__ src,
        const int* __restrict__ dst, const float* __restrict__ Wa,
        unsigned* __restrict__ degI, float* __restrict__ aggP,
        int N, int P, int epg) {
    __shared__ unsigned degH[PMAX];
    __shared__ float aggL[PMAX];
    const int g = blockIdx.x / NSLA, sl = blockIdx.x % NSLA;
    const int t = threadIdx.x;
    const int base = g * P, e0 = g * epg, e1 = e0 + epg;

    for (int j = t; j < P; j += NT) { degH[j] = 0u; aggL[j] = 0.0f; }
    __syncthreads();

    // full-graph in-degree histogram (every slice block needs all degrees)
    for (int e = e0 + t; e < e1; e += NT) {
        unsigned d = (unsigned)(dst[e] - base);
        if (d < (unsigned)P) atomicAdd(&degH[d], 1u);
    }
    __syncthreads();

    // scatter this slice's edges into LDS (hA recomputed from x on the fly)
    const float wa0 = Wa[0], wa1 = Wa[1];
    const float2* __restrict__ x2 = (const float2*)x;
    const int eps = (epg + NSLA - 1) / NSLA;
    const int s0 = e0 + sl * eps;
    int s1 = s0 + eps; if (s1 > e1) s1 = e1;
    for (int e = s0 + t; e < s1; e += NT) {
        unsigned s = (unsigned)(src[e] - base);
        unsigned d = (unsigned)(dst[e] - base);
        if (s < (unsigned)P && d < (unsigned)P) {
            float2 xv = x2[base + s];
            float hA = xv.x * wa0 + xv.y * wa1;
            float nrm = rsqrtf(1.0f + (float)degH[s]) * rsqrtf(1.0f + (float)degH[d]);
            atomicAdd(&aggL[d], hA * nrm);
        }
    }
    __syncthreads();

    // publish partial (plain coalesced stores; deterministic, no init needed)
    float* dstP = aggP + (size_t)sl * N + base;
    for (int j = t; j < P; j += NT) dstP[j] = aggL[j];
    if (sl == 0)
        for (int j = t; j < P; j += NT) degI[base + j] = degH[j];
}

// ===========================================================================
// K_B: one block per graph. score = sum of 4 partials + self term ->
// shuffle softmax -> keep/compact -> [membership scan only if kc>1] ->
// 3x(GCN+ReLU+BN) -> max-pool -> head -> log_softmax.
// ===========================================================================
__global__ __launch_bounds__(NT) void kB(
        const float* __restrict__ x, const int* __restrict__ src,
        const int* __restrict__ dst, const unsigned* __restrict__ degI,
        const float* __restrict__ aggP, const float* __restrict__ Wa,
        const float* __restrict__ bA, const float* __restrict__ wt,
        const float* __restrict__ W0, const float* __restrict__ b0,
        const float* __restrict__ g0, const float* __restrict__ be0,
        const float* __restrict__ m0, const float* __restrict__ v0,
        const float* __restrict__ W1, const float* __restrict__ b1,
        const float* __restrict__ g1, const float* __restrict__ be1,
        const float* __restrict__ m1, const float* __restrict__ v1,
        const float* __restrict__ W2, const float* __restrict__ b2,
        const float* __restrict__ g2, const float* __restrict__ be2,
        const float* __restrict__ m2, const float* __restrict__ v2,
        const float* __restrict__ Wf, const float* __restrict__ bfv,
        float* __restrict__ out, int N, int P, int epg) {
    const int g = blockIdx.x, t = threadIdx.x;
    const int lane = t & 63, wid = t >> 6;       // 16 waves
    const int base = g * P;
    const int e0 = g * epg, e1 = e0 + epg;

    __shared__ float scL[PMAX];
    __shared__ float hbufL[KSEG * HDIM], tbufL[KSEG * HDIM], redM[8 * HDIM];
    __shared__ float redA[16], redB[16], mzS[2];
    __shared__ int   keptL[KSEG];
    __shared__ float degkL[KSEG], pooledL[HDIM];
    __shared__ int   aSL[ESEG], aDL[ESEG];
    __shared__ int   kcnt, ecnt;

    if (t == 0) { kcnt = 0; ecnt = 0; }
    if (t < KSEG) degkL[t] = 1.0f;               // self-loop
    const float wa0 = Wa[0], wa1 = Wa[1], ba = bA[0], wtk = wt[0];
    const float2* __restrict__ x2 = (const float2*)x;

    // ---- score: sum 4 partials (fixed order) + self term; max reduce ----
    float m = -INFINITY;
    for (int j = t; j < P; j += NT) {
        int i = base + j;
        float a = aggP[i] + aggP[(size_t)N + i] +
                  aggP[2*(size_t)N + i] + aggP[3*(size_t)N + i];
        float dg = 1.0f + (float)degI[i];
        float2 xv = x2[i];
        float hA = xv.x * wa0 + xv.y * wa1;
        float sc = (a + hA * (1.0f / dg) + ba) * wtk;
        scL[j] = sc;
        m = fmaxf(m, sc);
    }
    #pragma unroll
    for (int off = 32; off; off >>= 1) m = fmaxf(m, __shfl_xor(m, off));
    if (lane == 0) redA[wid] = m;
    __syncthreads();
    if (wid == 0) {
        float v = (lane < 16) ? redA[lane] : -INFINITY;
        #pragma unroll
        for (int off = 8; off; off >>= 1) v = fmaxf(v, __shfl_xor(v, off));
        if (lane == 0) mzS[0] = v;
    }
    __syncthreads();
    m = mzS[0];

    // ---- z = sum exp(s - m) ----
    float z = 0.0f;
    for (int j = t; j < P; j += NT) z += expf(scL[j] - m);
    #pragma unroll
    for (int off = 32; off; off >>= 1) z += __shfl_xor(z, off);
    if (lane == 0) redB[wid] = z;
    __syncthreads();
    if (wid == 0) {
        float v = (lane < 16) ? redB[lane] : 0.0f;
        #pragma unroll
        for (int off = 8; off; off >>= 1) v += __shfl_xor(v, off);
        if (lane == 0) mzS[1] = v;
    }
    __syncthreads();
    const float zz = mzS[1];
    // argmax node has exp(0)=1 exactly -> smax = 1/zz (matches reference)
    const float thr = fminf(1.0f / zz - TOLV, MINSCORE);

    // ---- keep + compact; layer-0 rows h0 = x * score ----
    for (int j = t; j < P; j += NT) {
        float sc = expf(scL[j] - m) / zz;
        if (sc > thr) {
            int k = atomicAdd(&kcnt, 1);
            if (k < KSEG) {
                keptL[k] = j;
                float2 xv = x2[base + j];
                hbufL[k * HDIM + 0] = xv.x * sc;
                hbufL[k * HDIM + 1] = xv.y * sc;
            }
        }
    }
    __syncthreads();
    const int kc = kcnt < KSEG ? kcnt : KSEG;

    // ---- membership scan ONLY if more than one node kept ----
    int ec = 0;
    if (kc > 1) {
        for (int e = e0 + t; e < e1; e += NT) {
            int s = src[e] - base, d = dst[e] - base;
            int ks = -1, kd = -1;
            for (int q = 0; q < kc; ++q) {
                int kq = keptL[q];
                if (s == kq) ks = q;
                if (d == kq) kd = q;
            }
            if (ks >= 0 && kd >= 0) {
                int ee = atomicAdd(&ecnt, 1);
                if (ee < ESEG) { aSL[ee] = ks; aDL[ee] = kd; }
                atomicAdd(&degkL[kd], 1.0f);
            }
        }
        __syncthreads();
        ec = ecnt < ESEG ? ecnt : ESEG;
    }

    // ---- 3 GCN layers on kc rows ----
    const int c   = t & (HDIM - 1);
    const int sub = t >> 7;                     // 0..7 split-K groups
    const float* Ws[3]  = {W0, W1, W2};
    const float* bs[3]  = {b0, b1, b2};
    const float* gs[3]  = {g0, g1, g2};
    const float* bes[3] = {be0, be1, be2};
    const float* ms[3]  = {m0, m1, m2};
    const float* vs[3]  = {v0, v1, v2};

    for (int l = 0; l < 3; ++l) {
        const float* W = Ws[l];
        if (l == 0) {
            for (int r = sub; r < kc; r += 8)
                tbufL[r*HDIM+c] = hbufL[r*HDIM+0]*W[c] + hbufL[r*HDIM+1]*W[HDIM+c];
            __syncthreads();
        } else {
            for (int r = 0; r < kc; ++r) {
                float acc = 0.0f;
                const int k0i = sub * 16;
                #pragma unroll
                for (int i = 0; i < 16; ++i)
                    acc += hbufL[r*HDIM+k0i+i] * W[(k0i+i)*HDIM+c];
                redM[sub*HDIM+c] = acc;
                __syncthreads();
                if (t < HDIM) {
                    float s2 = 0.0f;
                    #pragma unroll
                    for (int q = 0; q < 8; ++q) s2 += redM[q*HDIM+c];
                    tbufL[r*HDIM+c] = s2;
                }
                __syncthreads();
            }
        }
        const float bb = bs[l][c];
        const float bscale = gs[l][c] * rsqrtf(vs[l][c] + EPSV);
        const float bmu = ms[l][c], bbe = bes[l][c];
        if (kc == 1) {
            // all active edges are self-edges; agg + self term == t exactly
            if (t < HDIM) {
                float v = tbufL[c] + bb;
                v = fmaxf(v, 0.0f);
                hbufL[c] = (v - bmu) * bscale + bbe;
            }
            __syncthreads();
        } else {
            for (int r = sub; r < kc; r += 8) {
                float a = 0.0f;
                for (int e = 0; e < ec; ++e) {
                    if (aDL[e] == r) {
                        int rs = aSL[e];
                        a += tbufL[rs*HDIM+c] * rsqrtf(degkL[rs]) * rsqrtf(degkL[r]);
                    }
                }
                float v = a + tbufL[r*HDIM+c] * (1.0f/degkL[r]) + bb;
                v = fmaxf(v, 0.0f);
                hbufL[r*HDIM+c] = (v - bmu) * bscale + bbe;
            }
            __syncthreads();
        }
    }

    // ---- max-pool over kept rows ----
    if (t < HDIM) {
        float mm = -INFINITY;
        for (int r = 0; r < kc; ++r) mm = fmaxf(mm, hbufL[r*HDIM+t]);
        pooledL[t] = mm;
    }
    __syncthreads();

    // ---- head: wave r (r<3) computes logits[r] ----
    if (wid < 3) {
        float acc = pooledL[lane]      * Wf[lane*3+wid] +
                    pooledL[lane + 64] * Wf[(lane+64)*3+wid];
        #pragma unroll
        for (int off = 32; off; off >>= 1) acc += __shfl_xor(acc, off);
        if (lane == 0) redA[wid] = acc + bfv[wid];
    }
    __syncthreads();
    if (t == 0) {
        float l0 = redA[0], l1 = redA[1], l2 = redA[2];
        float mm = fmaxf(l0, fmaxf(l1, l2));
        float zs = expf(l0-mm) + expf(l1-mm) + expf(l2-mm);
        float lz = logf(zs) + mm;
        out[g*3+0] = l0 - lz;
        out[g*3+1] = l1 - lz;
        out[g*3+2] = l2 - lz;
    }
}

// ===========================================================================

extern "C" void kernel_launch(void* const* d_in, const int* in_sizes, int n_in,
                              void* d_out, int out_size, void* d_ws, size_t ws_size,
                              hipStream_t stream) {
    const float* x      = (const float*)d_in[0];
    const int*   src    = (const int*)d_in[1];
    const int*   dst    = (const int*)d_in[2];
    const float* W_attn = (const float*)d_in[5];
    const float* b_attn = (const float*)d_in[6];
    const float* w_topk = (const float*)d_in[7];
    float* out = (float*)d_out;

    int N  = in_sizes[3];
    int E  = in_sizes[1];
    int Gn = out_size / 3;
    int Pn = N / Gn;
    int epg = E / Gn;

    // workspace: aggP[NSLA][N] | degI[N]   (no zero-init required anywhere)
    char* w = (char*)d_ws;
    auto alloc = [&](size_t bytes) -> void* {
        void* q = (void*)w;
        w += (bytes + 255) & ~size_t(255);
        return q;
    };
    float*    aggP = (float*)alloc((size_t)NSLA * N * 4);
    unsigned* degI = (unsigned*)alloc((size_t)N * 4);

    kA<<<Gn * NSLA, NT, 0, stream>>>(x, src, dst, W_attn, degI, aggP, N, Pn, epg);
    kB<<<Gn, NT, 0, stream>>>(x, src, dst, degI, aggP, W_attn, b_attn, w_topk,
        (const float*)d_in[8],  (const float*)d_in[9],  (const float*)d_in[10],
        (const float*)d_in[11], (const float*)d_in[12], (const float*)d_in[13],
        (const float*)d_in[14], (const float*)d_in[15], (const float*)d_in[16],
        (const float*)d_in[17], (const float*)d_in[18], (const float*)d_in[19],
        (const float*)d_in[20], (const float*)d_in[21], (const float*)d_in[22],
        (const float*)d_in[23], (const float*)d_in[24], (const float*)d_in[25],
        (const float*)d_in[26], (const float*)d_in[27], out, N, Pn, epg);
}

// Round 11
// 23.878 us; speedup vs baseline: 7.8701x; 1.0091x over previous
//
#include <hip/hip_runtime.h>
#include <math.h>

#define HDIM 128
#define EPSV 1e-5f
#define TOLV 1e-7f
#define MINSCORE 0.1f
#define PMAX 2048
#define KSEG 16
#define ESEG 64
#define NT 1024
#define NSLA 4          // partial-agg slices per graph
#define EIT  16         // max histogram iterations (epg <= EIT*NT)

// ===========================================================================
// K_A: 4 blocks per graph. Full per-graph LDS degree histogram (slice's own
// 4 edges register-cached during the pass), then scatter the slice from regs
// into LDS, publish private partial aggP[sl] (plain stores, no global
// atomics, no zero-init). Slice 0 also publishes hSelf = hA/deg + b.
// Slices are ITERATION-blocks: edge e = e0 + i*NT + t belongs to slice i>>2.
// ===========================================================================
__global__ __launch_bounds__(NT) void kA(
        const float* __restrict__ x, const int* __restrict__ src,
        const int* __restrict__ dst, const float* __restrict__ Wa,
        const float* __restrict__ bA, float* __restrict__ hSelf,
        float* __restrict__ aggP, int N, int P, int epg) {
    __shared__ unsigned degH[PMAX];
    __shared__ float aggL[PMAX];
    const int g = blockIdx.x / NSLA, sl = blockIdx.x % NSLA;
    const int t = threadIdx.x;
    const int base = g * P, e0 = g * epg, e1 = e0 + epg;

    for (int j = t; j < P; j += NT) { degH[j] = 0u; aggL[j] = 0.0f; }
    __syncthreads();

    // full-graph in-degree histogram; cache this slice's edges in registers
    int sR[NSLA], dR[NSLA];
    #pragma unroll
    for (int q = 0; q < NSLA; ++q) { sR[q] = -1; dR[q] = -1; }
    #pragma unroll
    for (int i = 0; i < EIT; ++i) {
        int e = e0 + i * NT + t;
        if (e < e1) {
            int dd = dst[e] - base;
            if ((unsigned)dd < (unsigned)P) atomicAdd(&degH[dd], 1u);
            if ((i >> 2) == sl) {
                sR[i & 3] = src[e] - base;
                dR[i & 3] = dd;
            }
        }
    }
    __syncthreads();

    // scatter this slice's edges (from registers) into LDS
    const float wa0 = Wa[0], wa1 = Wa[1];
    const float2* __restrict__ x2 = (const float2*)x;
    #pragma unroll
    for (int q = 0; q < NSLA; ++q) {
        unsigned s = (unsigned)sR[q], d = (unsigned)dR[q];
        if (s < (unsigned)P && d < (unsigned)P) {
            float2 xv = x2[base + s];
            float hA = xv.x * wa0 + xv.y * wa1;
            float nrm = rsqrtf(1.0f + (float)degH[s]) * rsqrtf(1.0f + (float)degH[d]);
            atomicAdd(&aggL[d], hA * nrm);
        }
    }
    __syncthreads();

    // publish partial (plain coalesced stores)
    float* dstP = aggP + (size_t)sl * N + base;
    for (int j = t; j < P; j += NT) dstP[j] = aggL[j];
    if (sl == 0) {
        const float ba = bA[0];
        for (int j = t; j < P; j += NT) {
            float2 xv = x2[base + j];
            float hA = xv.x * wa0 + xv.y * wa1;
            hSelf[base + j] = hA * (1.0f / (1.0f + (float)degH[j])) + ba;
        }
    }
}

// ===========================================================================
// K_B: one block per graph. score = sum 4 partials + hSelf -> shuffle
// softmax (exp cached in LDS) -> keep/compact -> [membership only if kc>1]
// -> 3x(GCN+ReLU+BN) -> pool -> head -> log_softmax.
// ===========================================================================
__global__ __launch_bounds__(NT) void kB(
        const float* __restrict__ x, const int* __restrict__ src,
        const int* __restrict__ dst, const float* __restrict__ hSelf,
        const float* __restrict__ aggP,
        const float* __restrict__ wt,
        const float* __restrict__ W0, const float* __restrict__ b0,
        const float* __restrict__ g0, const float* __restrict__ be0,
        const float* __restrict__ m0, const float* __restrict__ v0,
        const float* __restrict__ W1, const float* __restrict__ b1,
        const float* __restrict__ g1, const float* __restrict__ be1,
        const float* __restrict__ m1, const float* __restrict__ v1,
        const float* __restrict__ W2, const float* __restrict__ b2,
        const float* __restrict__ g2, const float* __restrict__ be2,
        const float* __restrict__ m2, const float* __restrict__ v2,
        const float* __restrict__ Wf, const float* __restrict__ bfv,
        float* __restrict__ out, int N, int P, int epg) {
    const int g = blockIdx.x, t = threadIdx.x;
    const int lane = t & 63, wid = t >> 6;       // 16 waves
    const int base = g * P;
    const int e0 = g * epg, e1 = e0 + epg;

    __shared__ float scL[PMAX];
    __shared__ float hbufL[KSEG * HDIM], tbufL[KSEG * HDIM], redM[8 * HDIM];
    __shared__ float redA[16], redB[16], mzS[2];
    __shared__ int   keptL[KSEG];
    __shared__ float degkL[KSEG], pooledL[HDIM];
    __shared__ int   aSL[ESEG], aDL[ESEG];
    __shared__ int   kcnt, ecnt;

    if (t == 0) { kcnt = 0; ecnt = 0; }
    if (t < KSEG) degkL[t] = 1.0f;               // self-loop
    const float wtk = wt[0];
    const float2* __restrict__ x2 = (const float2*)x;

    // ---- score: 4 partials (fixed order) + hSelf; max reduce ----
    float m = -INFINITY;
    for (int j = t; j < P; j += NT) {
        int i = base + j;
        float a = aggP[i] + aggP[(size_t)N + i] +
                  aggP[2*(size_t)N + i] + aggP[3*(size_t)N + i];
        float sc = (a + hSelf[i]) * wtk;
        scL[j] = sc;
        m = fmaxf(m, sc);
    }
    #pragma unroll
    for (int off = 32; off; off >>= 1) m = fmaxf(m, __shfl_xor(m, off));
    if (lane == 0) redA[wid] = m;
    __syncthreads();
    if (wid == 0) {
        float v = (lane < 16) ? redA[lane] : -INFINITY;
        #pragma unroll
        for (int off = 8; off; off >>= 1) v = fmaxf(v, __shfl_xor(v, off));
        if (lane == 0) mzS[0] = v;
    }
    __syncthreads();
    m = mzS[0];

    // ---- z = sum exp(s - m); cache exp back into scL ----
    float z = 0.0f;
    for (int j = t; j < P; j += NT) {
        float ex = expf(scL[j] - m);
        scL[j] = ex;
        z += ex;
    }
    __syncthreads();                             // scL writes done before reuse
    #pragma unroll
    for (int off = 32; off; off >>= 1) z += __shfl_xor(z, off);
    if (lane == 0) redB[wid] = z;
    __syncthreads();
    if (wid == 0) {
        float v = (lane < 16) ? redB[lane] : 0.0f;
        #pragma unroll
        for (int off = 8; off; off >>= 1) v += __shfl_xor(v, off);
        if (lane == 0) mzS[1] = v;
    }
    __syncthreads();
    const float zz = mzS[1];
    // argmax node has exp(0)=1 exactly -> smax = 1/zz (matches reference)
    const float thr = fminf(1.0f / zz - TOLV, MINSCORE);

    // ---- keep + compact; layer-0 rows h0 = x * score ----
    for (int j = t; j < P; j += NT) {
        float sc = scL[j] / zz;
        if (sc > thr) {
            int k = atomicAdd(&kcnt, 1);
            if (k < KSEG) {
                keptL[k] = j;
                float2 xv = x2[base + j];
                hbufL[k * HDIM + 0] = xv.x * sc;
                hbufL[k * HDIM + 1] = xv.y * sc;
            }
        }
    }
    __syncthreads();
    const int kc = kcnt < KSEG ? kcnt : KSEG;

    // ---- membership scan ONLY if more than one node kept ----
    int ec = 0;
    if (kc > 1) {
        for (int e = e0 + t; e < e1; e += NT) {
            int s = src[e] - base, d = dst[e] - base;
            int ks = -1, kd = -1;
            for (int q = 0; q < kc; ++q) {
                int kq = keptL[q];
                if (s == kq) ks = q;
                if (d == kq) kd = q;
            }
            if (ks >= 0 && kd >= 0) {
                int ee = atomicAdd(&ecnt, 1);
                if (ee < ESEG) { aSL[ee] = ks; aDL[ee] = kd; }
                atomicAdd(&degkL[kd], 1.0f);
            }
        }
        __syncthreads();
        ec = ecnt < ESEG ? ecnt : ESEG;
    }

    // ---- 3 GCN layers on kc rows ----
    const int c   = t & (HDIM - 1);
    const int sub = t >> 7;                     // 0..7 split-K groups
    const float* Ws[3]  = {W0, W1, W2};
    const float* bs[3]  = {b0, b1, b2};
    const float* gs[3]  = {g0, g1, g2};
    const float* bes[3] = {be0, be1, be2};
    const float* ms[3]  = {m0, m1, m2};
    const float* vs[3]  = {v0, v1, v2};

    for (int l = 0; l < 3; ++l) {
        const float* W = Ws[l];
        if (l == 0) {
            for (int r = sub; r < kc; r += 8)
                tbufL[r*HDIM+c] = hbufL[r*HDIM+0]*W[c] + hbufL[r*HDIM+1]*W[HDIM+c];
            __syncthreads();
        } else {
            for (int r = 0; r < kc; ++r) {
                float acc = 0.0f;
                const int k0i = sub * 16;
                #pragma unroll
                for (int i = 0; i < 16; ++i)
                    acc += hbufL[r*HDIM+k0i+i] * W[(k0i+i)*HDIM+c];
                redM[sub*HDIM+c] = acc;
                __syncthreads();
                if (t < HDIM) {
                    float s2 = 0.0f;
                    #pragma unroll
                    for (int q = 0; q < 8; ++q) s2 += redM[q*HDIM+c];
                    tbufL[r*HDIM+c] = s2;
                }
                __syncthreads();
            }
        }
        const float bb = bs[l][c];
        const float bscale = gs[l][c] * rsqrtf(vs[l][c] + EPSV);
        const float bmu = ms[l][c], bbe = bes[l][c];
        if (kc == 1) {
            // all active edges are self-edges; agg + self term == t exactly
            if (t < HDIM) {
                float v = tbufL[c] + bb;
                v = fmaxf(v, 0.0f);
                hbufL[c] = (v - bmu) * bscale + bbe;
            }
            __syncthreads();
        } else {
            for (int r = sub; r < kc; r += 8) {
                float a = 0.0f;
                for (int e = 0; e < ec; ++e) {
                    if (aDL[e] == r) {
                        int rs = aSL[e];
                        a += tbufL[rs*HDIM+c] * rsqrtf(degkL[rs]) * rsqrtf(degkL[r]);
                    }
                }
                float v = a + tbufL[r*HDIM+c] * (1.0f/degkL[r]) + bb;
                v = fmaxf(v, 0.0f);
                hbufL[r*HDIM+c] = (v - bmu) * bscale + bbe;
            }
            __syncthreads();
        }
    }

    // ---- max-pool over kept rows (kc==1: row 0 is the pool) ----
    if (t < HDIM) {
        float mm = hbufL[t];
        for (int r = 1; r < kc; ++r) mm = fmaxf(mm, hbufL[r*HDIM+t]);
        pooledL[t] = mm;
    }
    __syncthreads();

    // ---- head: wave r (r<3) computes logits[r] ----
    if (wid < 3) {
        float acc = pooledL[lane]      * Wf[lane*3+wid] +
                    pooledL[lane + 64] * Wf[(lane+64)*3+wid];
        #pragma unroll
        for (int off = 32; off; off >>= 1) acc += __shfl_xor(acc, off);
        if (lane == 0) redA[wid] = acc + bfv[wid];
    }
    __syncthreads();
    if (t == 0) {
        float l0 = redA[0], l1 = redA[1], l2 = redA[2];
        float mm = fmaxf(l0, fmaxf(l1, l2));
        float zs = expf(l0-mm) + expf(l1-mm) + expf(l2-mm);
        float lz = logf(zs) + mm;
        out[g*3+0] = l0 - lz;
        out[g*3+1] = l1 - lz;
        out[g*3+2] = l2 - lz;
    }
}

// ===========================================================================

extern "C" void kernel_launch(void* const* d_in, const int* in_sizes, int n_in,
                              void* d_out, int out_size, void* d_ws, size_t ws_size,
                              hipStream_t stream) {
    const float* x      = (const float*)d_in[0];
    const int*   src    = (const int*)d_in[1];
    const int*   dst    = (const int*)d_in[2];
    const float* W_attn = (const float*)d_in[5];
    const float* b_attn = (const float*)d_in[6];
    const float* w_topk = (const float*)d_in[7];
    float* out = (float*)d_out;

    int N  = in_sizes[3];
    int E  = in_sizes[1];
    int Gn = out_size / 3;
    int Pn = N / Gn;
    int epg = E / Gn;

    // workspace: aggP[NSLA][N] | hSelf[N]   (no zero-init required)
    char* w = (char*)d_ws;
    auto alloc = [&](size_t bytes) -> void* {
        void* q = (void*)w;
        w += (bytes + 255) & ~size_t(255);
        return q;
    };
    float* aggP  = (float*)alloc((size_t)NSLA * N * 4);
    float* hSelf = (float*)alloc((size_t)N * 4);

    kA<<<Gn * NSLA, NT, 0, stream>>>(x, src, dst, W_attn, b_attn, hSelf, aggP,
                                     N, Pn, epg);
    kB<<<Gn, NT, 0, stream>>>(x, src, dst, hSelf, aggP, w_topk,
        (const float*)d_in[8],  (const float*)d_in[9],  (const float*)d_in[10],
        (const float*)d_in[11], (const float*)d_in[12], (const float*)d_in[13],
        (const float*)d_in[14], (const float*)d_in[15], (const float*)d_in[16],
        (const float*)d_in[17], (const float*)d_in[18], (const float*)d_in[19],
        (const float*)d_in[20], (const float*)d_in[21], (const float*)d_in[22],
        (const float*)d_in[23], (const float*)d_in[24], (const float*)d_in[25],
        (const float*)d_in[26], (const float*)d_in[27], out, N, Pn, epg);
}